// Round 7
// baseline (85.551 us; speedup 1.0000x reference)
//
#include <hip/hip_runtime.h>
#include <math.h>

#define B 64
#define NI 1024
#define NO 1024
#define NC 10
#define ISPLIT 32
#define KSEG 32          // NI / ISPLIT
#define OBLK 64          // o per block
#define NOB (NO / OBLK)  // 16

typedef float f4 __attribute__((ext_vector_type(4)));
typedef _Float16 h8 __attribute__((ext_vector_type(8)));
typedef _Float16 h2 __attribute__((ext_vector_type(2)));

// log(tanh(100*ax)) for ax>=0 via hw exp/log: tanh(z) = 1 - 2/(e^{2z}+1).
// ax==0 -> log(0) = -inf -> clamp -60000 (f16-safe sentinel; sums of several
// sentinels overflow f16 to -inf, exp(-inf)=0 == masked product of zeros).
// Large ax: e=inf -> th=1 -> log 0 exactly.
__device__ __forceinline__ float lt_fast(float ax) {
    float e  = __expf(200.0f * ax);
    float th = 1.0f - 2.0f / (e + 1.0f);
    return fmaxf(__logf(th), -60000.0f);
}

// Partial (h,s) sums over k-segment `is` via MFMA 16x16x32 f16.
//   phs[is][o][b] = f16x2( sum_k x[b,k]*fcm[o,k],  sum_k lt[b,k]*m[o,k] )
// Block: 64-o tile x 32-k seg; 4 waves each own 16 o; grid 16*32 = 512.
template<bool FIRST>
__global__ __launch_bounds__(256, 2) void partial_k(
    const float* __restrict__ xraw,   // [B][NI]       (FIRST)
    const h2*    __restrict__ xp,     // [B][NI] (h,lt) (!FIRST)
    const float* __restrict__ fc,
    const float* __restrict__ v,
    h2* __restrict__ phs)             // [ISPLIT][NO][B]
{
    const int blk = blockIdx.x, t = threadIdx.x;
    const int ob = blk & (NOB - 1), is = blk >> 4;
    const int o0 = ob * OBLK, i0 = is * KSEG;

    // f16 tiles, [row][granule-of-8]; granule XOR-swizzled by ((row>>1)&3) so
    // MFMA fragment reads (16 lanes stride-64B) spread across all 32 banks.
    __shared__ h8 sWf[OBLK][4];   // fc*m
    __shared__ h8 sWm[OBLK][4];   // m
    __shared__ h8 sX [B][4];      // x
    __shared__ h8 sL [B][4];      // lt

    // ---- stage weights: thread = (o = t>>2, g = t&3), 32B contiguous ----
    {
        const int o = t >> 2, g = t & 3;
        const float* fp = &fc[(o0 + o) * NI + i0 + g * 8];
        const float* vp = &v [(o0 + o) * NI + i0 + g * 8];
        f4 fa = *(const f4*)fp, fb = *(const f4*)(fp + 4);
        f4 va = *(const f4*)vp, vb = *(const f4*)(vp + 4);
        h8 wf, wm;
        #pragma unroll
        for (int j = 0; j < 4; ++j) {
            bool ma = va[j] > 0.0f, mb = vb[j] > 0.0f;
            wf[j]     = ma ? (_Float16)fa[j] : (_Float16)0.0f;
            wm[j]     = ma ? (_Float16)1.0f  : (_Float16)0.0f;
            wf[4 + j] = mb ? (_Float16)fb[j] : (_Float16)0.0f;
            wm[4 + j] = mb ? (_Float16)1.0f  : (_Float16)0.0f;
        }
        const int gs = g ^ ((o >> 1) & 3);
        sWf[o][gs] = wf;
        sWm[o][gs] = wm;
    }
    // ---- stage activations: thread = (b = t>>2, g = t&3) ----
    {
        const int b = t >> 2, g = t & 3;
        h8 xv, lv;
        if (FIRST) {
            const float* xr = &xraw[b * NI + i0 + g * 8];
            f4 xa = *(const f4*)xr, xb = *(const f4*)(xr + 4);
            #pragma unroll
            for (int j = 0; j < 4; ++j) {
                xv[j]     = (_Float16)xa[j];
                lv[j]     = (_Float16)lt_fast(fabsf(xa[j]));
                xv[4 + j] = (_Float16)xb[j];
                lv[4 + j] = (_Float16)lt_fast(fabsf(xb[j]));
            }
        } else {
            const f4* s4 = (const f4*)&xp[b * NI + i0 + g * 8];
            f4 q0 = s4[0], q1 = s4[1];
            #pragma unroll
            for (int j = 0; j < 4; ++j) {
                h2 p0 = __builtin_bit_cast(h2, q0[j]);
                h2 p1 = __builtin_bit_cast(h2, q1[j]);
                xv[j] = p0.x;     lv[j] = p0.y;
                xv[4 + j] = p1.x; lv[4 + j] = p1.y;
            }
        }
        const int gs = g ^ ((b >> 1) & 3);
        sX[b][gs] = xv;
        sL[b][gs] = lv;
    }
    __syncthreads();

    // ---- MFMA: wave w -> o rows [16w,16w+16); 4 b-quadrants ----
    const int w = t >> 6, l = t & 63;
    const int r16 = l & 15, gsel = l >> 4;
    const int swz = gsel ^ ((r16 >> 1) & 3);   // (row>>1)&3 == (r16>>1)&3: 16|row-offsets
    h8 aF = sWf[w * 16 + r16][swz];
    h8 aM = sWm[w * 16 + r16][swz];
    f4 accH[4] = {}, accS[4] = {};
    #pragma unroll
    for (int bq = 0; bq < 4; ++bq) {
        h8 bX = sX[bq * 16 + r16][swz];
        h8 bL = sL[bq * 16 + r16][swz];
        accH[bq] = __builtin_amdgcn_mfma_f32_16x16x32_f16(aF, bX, accH[bq], 0, 0, 0);
        accS[bq] = __builtin_amdgcn_mfma_f32_16x16x32_f16(aM, bL, accS[bq], 0, 0, 0);
    }

    // ---- store: D row = gsel*4 + r (o), col = r16 (b) [m89 layout] ----
    const int obase = (is * NO + o0 + w * 16 + gsel * 4) * B;
    #pragma unroll
    for (int bq = 0; bq < 4; ++bq)
        #pragma unroll
        for (int r = 0; r < 4; ++r) {
            h2 pv;
            pv.x = (_Float16)accH[bq][r];
            pv.y = (_Float16)accS[bq][r];
            phs[obase + r * B + bq * 16 + r16] = pv;
        }
}

// Reduce splits, h0 = relu(sh*exp(ss)); emit pair layout xp[b][o]=(h,lt) for
// the next layer's staging and xh[o][b]=h (f16) for the head kernel; zero y.
__global__ __launch_bounds__(256) void final0_k(
    const h2* __restrict__ phs, h2* __restrict__ xp, _Float16* __restrict__ xh,
    float* __restrict__ y)
{
    const int g = blockIdx.x * 256 + threadIdx.x;
    if (g < B * NC) y[g] = 0.0f;
    const int o = g >> 6, b = g & 63;
    float sh = 0.f, ss = 0.f;
    #pragma unroll
    for (int sp = 0; sp < ISPLIT; ++sp) {
        h2 p = phs[(sp * NO + o) * B + b];
        sh += (float)p.x;
        ss += (float)p.y;
    }
    float h = fmaxf(sh * __expf(ss), 0.0f);
    h2 pr; pr.x = (_Float16)h; pr.y = (_Float16)lt_fast(h);
    xp[b * NI + o] = pr;          // scattered 4B, L2-absorbed (256 KB total)
    xh[o * B + b] = (_Float16)h;  // coalesced
}

// Finalize layer-1 for a 4-o chunk + both heads; atomicAdd into y.
__global__ __launch_bounds__(256) void final1_head_k(
    const h2* __restrict__ phs, const _Float16* __restrict__ xh,
    const float* __restrict__ hd0, const float* __restrict__ hd1,
    float* __restrict__ y)
{
    const int blk = blockIdx.x, t = threadIdx.x;
    const int o0 = blk * 4;
    __shared__ h2 hsm[4][B];      // (h0, h1)
    const int ol = t >> 6, b = t & 63;
    float sh = 0.f, ss = 0.f;
    #pragma unroll
    for (int sp = 0; sp < ISPLIT; ++sp) {
        h2 p = phs[(sp * NO + o0 + ol) * B + b];
        sh += (float)p.x;
        ss += (float)p.y;
    }
    float h1 = fmaxf(sh * __expf(ss), 0.0f);
    h2 pr; pr.x = xh[(o0 + ol) * B + b]; pr.y = (_Float16)h1;
    hsm[ol][b] = pr;
    __syncthreads();
    #pragma unroll
    for (int pass = 0; pass < 3; ++pass) {
        const int idx = t + pass * 256;
        if (idx < NC * B) {
            const int c = idx >> 6, bb = idx & 63;
            float acc = 0.f;
            #pragma unroll
            for (int oo = 0; oo < 4; ++oo) {
                h2 hp = hsm[oo][bb];
                acc += (float)hp.x * hd0[c * NO + o0 + oo]
                     + (float)hp.y * hd1[c * NO + o0 + oo];
            }
            atomicAdd(&y[bb * NC + c], acc);
        }
    }
}

extern "C" void kernel_launch(void* const* d_in, const int* in_sizes, int n_in,
                              void* d_out, int out_size, void* d_ws, size_t ws_size,
                              hipStream_t stream) {
    const float* x   = (const float*)d_in[0];
    const float* v0  = (const float*)d_in[1];
    const float* fc0 = (const float*)d_in[2];
    const float* hd0 = (const float*)d_in[3];
    const float* v1  = (const float*)d_in[4];
    const float* fc1 = (const float*)d_in[5];
    const float* hd1 = (const float*)d_in[6];
    float* y = (float*)d_out;

    h2* phs      = (h2*)d_ws;                                   // 8 MB
    h2* xp       = phs + (size_t)ISPLIT * NO * B;               // 256 KB
    _Float16* xh = (_Float16*)(xp + (size_t)B * NI);            // 128 KB

    partial_k<true ><<<512, 256, 0, stream>>>(x, nullptr, fc0, v0, phs);
    final0_k        <<<256, 256, 0, stream>>>(phs, xp, xh, y);
    partial_k<false><<<512, 256, 0, stream>>>(nullptr, xp, fc1, v1, phs);
    final1_head_k   <<<256, 256, 0, stream>>>(phs, xh, hd1 ? hd0 : hd0, hd1, y);
}

// Round 8
// 26.038 us; speedup vs baseline: 3.2856x; 3.2856x over previous
//
#include <hip/hip_runtime.h>
#include <math.h>

#define B 64
#define NI 1024
#define NO 1024
#define NC 10
#define ISPLIT 16
#define KSEG 64          // NI / ISPLIT
#define OBLK 64          // o per block
#define NOB (NO / OBLK)  // 16

typedef float f4 __attribute__((ext_vector_type(4)));
typedef float f2 __attribute__((ext_vector_type(2)));
typedef _Float16 h8 __attribute__((ext_vector_type(8)));
typedef _Float16 h2 __attribute__((ext_vector_type(2)));

// log(tanh(100*ax)) for ax>=0 via hw exp/log: tanh(z) = 1 - 2/(e^{2z}+1).
// ax==0 -> log(0) = -inf -> clamp -60000 (f16-safe sentinel; >=2 sentinels
// overflow f16 to -inf, exp(-inf)=0 == masked product containing a zero).
// Large ax: e=inf -> th=1 -> log = 0 exactly.
__device__ __forceinline__ float lt_fast(float ax) {
    float e  = __expf(200.0f * ax);
    float th = 1.0f - 2.0f / (e + 1.0f);
    return fmaxf(__logf(th), -60000.0f);
}

// Partial (h,s) sums over 64-k segment `is` via MFMA 16x16x32 f16.
//   phs[is][o][b] = f16x2( sum_k x[b,k]*fc[o,k]*m, sum_k lt[b,k]*m )
// Block: 64 o x 64 k; 4 waves each own 16 o; grid NOB*ISPLIT = 256.
// LDS granule = h8 (8 k's, 16B), index XOR-swizzled by (row&7): fragment
// reads spread over all 8 granule-columns -> all 32 banks, 2-way max.
template<bool FIRST>
__global__ __launch_bounds__(256, 2) void partial_k(
    const float* __restrict__ xraw,   // [B][NI]        (FIRST)
    const h2*    __restrict__ xp,     // [B][NI] (h,lt) (!FIRST)
    const float* __restrict__ fc,
    const float* __restrict__ v,
    h2* __restrict__ phs)             // [ISPLIT][NO][B]
{
    const int blk = blockIdx.x, t = threadIdx.x;
    const int ob = blk & (NOB - 1), is = blk >> 4;
    const int o0 = ob * OBLK, i0 = is * KSEG;

    __shared__ h8 sWf[OBLK][8];   // fc*m   8 KB
    __shared__ h8 sWm[OBLK][8];   // m      8 KB
    __shared__ h8 sX [B][8];      // x      8 KB
    __shared__ h8 sL [B][8];      // lt     8 KB

    // ---- stage weights: thread = (o = t>>2, q = t&3), 64B contiguous ----
    {
        const int o = t >> 2, q = t & 3;
        const float* fp = &fc[(o0 + o) * NI + i0 + q * 16];
        const float* vp = &v [(o0 + o) * NI + i0 + q * 16];
        #pragma unroll
        for (int gg = 0; gg < 2; ++gg) {
            f4 fa = *(const f4*)(fp + gg * 8), fb = *(const f4*)(fp + gg * 8 + 4);
            f4 va = *(const f4*)(vp + gg * 8), vb = *(const f4*)(vp + gg * 8 + 4);
            h8 wf, wm;
            #pragma unroll
            for (int j = 0; j < 4; ++j) {
                bool ma = va[j] > 0.0f, mb = vb[j] > 0.0f;
                wf[j]     = ma ? (_Float16)fa[j] : (_Float16)0.0f;
                wm[j]     = ma ? (_Float16)1.0f  : (_Float16)0.0f;
                wf[4 + j] = mb ? (_Float16)fb[j] : (_Float16)0.0f;
                wm[4 + j] = mb ? (_Float16)1.0f  : (_Float16)0.0f;
            }
            const int g = q * 2 + gg;
            sWf[o][g ^ (o & 7)] = wf;
            sWm[o][g ^ (o & 7)] = wm;
        }
    }
    // ---- stage activations: thread = (b = t>>2, q = t&3) ----
    {
        const int b = t >> 2, q = t & 3;
        if (FIRST) {
            const float* xr = &xraw[b * NI + i0 + q * 16];
            #pragma unroll
            for (int gg = 0; gg < 2; ++gg) {
                f4 xa = *(const f4*)(xr + gg * 8), xb = *(const f4*)(xr + gg * 8 + 4);
                h8 xv, lv;
                #pragma unroll
                for (int j = 0; j < 4; ++j) {
                    xv[j]     = (_Float16)xa[j];
                    lv[j]     = (_Float16)lt_fast(fabsf(xa[j]));
                    xv[4 + j] = (_Float16)xb[j];
                    lv[4 + j] = (_Float16)lt_fast(fabsf(xb[j]));
                }
                const int g = q * 2 + gg;
                sX[b][g ^ (b & 7)] = xv;
                sL[b][g ^ (b & 7)] = lv;
            }
        } else {
            const f4* s4 = (const f4*)&xp[b * NI + i0 + q * 16];  // 16 pairs = 4xf4
            #pragma unroll
            for (int gg = 0; gg < 2; ++gg) {
                f4 q0 = s4[gg * 2], q1 = s4[gg * 2 + 1];
                h8 xv, lv;
                #pragma unroll
                for (int j = 0; j < 4; ++j) {
                    h2 p0 = __builtin_bit_cast(h2, q0[j]);
                    h2 p1 = __builtin_bit_cast(h2, q1[j]);
                    xv[j] = p0.x;     lv[j] = p0.y;
                    xv[4 + j] = p1.x; lv[4 + j] = p1.y;
                }
                const int g = q * 2 + gg;
                sX[b][g ^ (b & 7)] = xv;
                sL[b][g ^ (b & 7)] = lv;
            }
        }
    }
    __syncthreads();

    // ---- MFMA: wave w -> o rows [16w,16w+16); 4 b-quadrants x 2 k-halves ----
    const int w = t >> 6, l = t & 63;
    const int r16 = l & 15, ks = l >> 4;
    const int sw0 = ks ^ (r16 & 7), sw1 = (ks + 4) ^ (r16 & 7);
    h8 aF0 = sWf[w * 16 + r16][sw0], aF1 = sWf[w * 16 + r16][sw1];
    h8 aM0 = sWm[w * 16 + r16][sw0], aM1 = sWm[w * 16 + r16][sw1];
    f4 accH[4] = {}, accS[4] = {};
    #pragma unroll
    for (int bq = 0; bq < 4; ++bq) {
        h8 bX0 = sX[bq * 16 + r16][sw0], bX1 = sX[bq * 16 + r16][sw1];
        h8 bL0 = sL[bq * 16 + r16][sw0], bL1 = sL[bq * 16 + r16][sw1];
        accH[bq] = __builtin_amdgcn_mfma_f32_16x16x32_f16(aF0, bX0, accH[bq], 0, 0, 0);
        accH[bq] = __builtin_amdgcn_mfma_f32_16x16x32_f16(aF1, bX1, accH[bq], 0, 0, 0);
        accS[bq] = __builtin_amdgcn_mfma_f32_16x16x32_f16(aM0, bL0, accS[bq], 0, 0, 0);
        accS[bq] = __builtin_amdgcn_mfma_f32_16x16x32_f16(aM1, bL1, accS[bq], 0, 0, 0);
    }

    // ---- store: D row = ks*4 + r (o), col = r16 (b) [m89 layout] ----
    const int obase = (is * NO + o0 + w * 16 + ks * 4) * B;
    #pragma unroll
    for (int bq = 0; bq < 4; ++bq)
        #pragma unroll
        for (int r = 0; r < 4; ++r) {
            h2 pv;
            pv.x = (_Float16)accH[bq][r];
            pv.y = (_Float16)accS[bq][r];
            phs[obase + r * B + bq * 16 + r16] = pv;
        }
}

// Reduce splits, h0 = relu(sh*exp(ss)); emit xp[b][o]=(h,lt) for layer-1
// staging and xh0[o][b]=h (f16) for the head; zero y.
__global__ __launch_bounds__(256) void final0_k(
    const h2* __restrict__ phs, h2* __restrict__ xp, _Float16* __restrict__ xh0,
    float* __restrict__ y)
{
    const int g = blockIdx.x * 256 + threadIdx.x;
    if (g < B * NC) y[g] = 0.0f;
    const int o = g >> 6, b = g & 63;
    float sh = 0.f, ss = 0.f;
    #pragma unroll
    for (int sp = 0; sp < ISPLIT; ++sp) {
        h2 p = phs[(sp * NO + o) * B + b];
        sh += (float)p.x;
        ss += (float)p.y;
    }
    float h = fmaxf(sh * __expf(ss), 0.0f);
    h2 pr; pr.x = (_Float16)h; pr.y = (_Float16)lt_fast(h);
    xp[b * NI + o]  = pr;          // scattered 4B, L2-absorbed (256 KB)
    xh0[o * B + b] = (_Float16)h;  // coalesced
}

// Reduce splits for layer 1 -> xh1[o][b] = h1 (f16). No atomics.
__global__ __launch_bounds__(256) void final1_k(
    const h2* __restrict__ phs, _Float16* __restrict__ xh1)
{
    const int g = blockIdx.x * 256 + threadIdx.x;
    const int o = g >> 6, b = g & 63;
    float sh = 0.f, ss = 0.f;
    #pragma unroll
    for (int sp = 0; sp < ISPLIT; ++sp) {
        h2 p = phs[(sp * NO + o) * B + b];
        sh += (float)p.x;
        ss += (float)p.y;
    }
    xh1[o * B + b] = (_Float16)fmaxf(sh * __expf(ss), 0.0f);
}

// Heads: block = 64-o chunk (grid 16). y zeroed by final0_k; 16-contender
// atomics only (R6-proven cheap).
__global__ __launch_bounds__(256) void head_k(
    const _Float16* __restrict__ xh0, const _Float16* __restrict__ xh1,
    const float* __restrict__ hd0, const float* __restrict__ hd1,
    float* __restrict__ y)
{
    const int blk = blockIdx.x, t = threadIdx.x;
    const int o0 = blk * 64;
    __shared__ h2 hh[64][B];      // (h0, h1)  16 KB
    __shared__ f2 hdl[NC][64];    // (hd0, hd1) 5 KB

    #pragma unroll
    for (int rep = 0; rep < 16; ++rep) {
        const int cell = t + rep * 256;
        const int ol = cell >> 6, b = cell & 63;
        h2 e;
        e.x = xh0[(o0 + ol) * B + b];
        e.y = xh1[(o0 + ol) * B + b];
        hh[ol][b] = e;
    }
    for (int e = t; e < NC * 64; e += 256) {
        const int c = e >> 6, ol = e & 63;
        f2 d; d.x = hd0[c * NO + o0 + ol]; d.y = hd1[c * NO + o0 + ol];
        hdl[c][ol] = d;
    }
    __syncthreads();

    const int w = t >> 6, lane = t & 63;
    for (int cc = w; cc < NC; cc += 4) {
        float acc = 0.f;
        #pragma unroll 8
        for (int ol = 0; ol < 64; ++ol) {
            h2 hv = hh[ol][lane];           // 256B-stride column, 2-way max
            f2 dv = hdl[cc][ol];            // wave-uniform broadcast
            acc = fmaf((float)hv.x, dv.x, fmaf((float)hv.y, dv.y, acc));
        }
        atomicAdd(&y[lane * NC + cc], acc);
    }
}

extern "C" void kernel_launch(void* const* d_in, const int* in_sizes, int n_in,
                              void* d_out, int out_size, void* d_ws, size_t ws_size,
                              hipStream_t stream) {
    const float* x   = (const float*)d_in[0];
    const float* v0  = (const float*)d_in[1];
    const float* fc0 = (const float*)d_in[2];
    const float* hd0 = (const float*)d_in[3];
    const float* v1  = (const float*)d_in[4];
    const float* fc1 = (const float*)d_in[5];
    const float* hd1 = (const float*)d_in[6];
    float* y = (float*)d_out;

    h2* phs       = (h2*)d_ws;                          // 16*1024*64*4B = 4 MB
    h2* xp        = phs + (size_t)ISPLIT * NO * B;      // 256 KB
    _Float16* xh0 = (_Float16*)(xp + (size_t)B * NI);   // 128 KB
    _Float16* xh1 = xh0 + (size_t)NO * B;               // 128 KB

    partial_k<true ><<<NOB * ISPLIT, 256, 0, stream>>>(x, nullptr, fc0, v0, phs);
    final0_k        <<<256, 256, 0, stream>>>(phs, xp, xh0, y);
    partial_k<false><<<NOB * ISPLIT, 256, 0, stream>>>(nullptr, xp, fc1, v1, phs);
    final1_k        <<<256, 256, 0, stream>>>(phs, xh1);
    head_k          <<<16,  256, 0, stream>>>(xh0, xh1, hd0, hd1, y);
}